// Round 1
// baseline (483.621 us; speedup 1.0000x reference)
//
#include <hip/hip_runtime.h>
#include <math.h>

// Problem dims (fixed by setup_inputs):
// x [2,64,16,64,64], y [2,128,8,32,32]
// w_down_h [64,128], w_down_l [64,64], w_flow [3,128,3,3,3],
// w_att_atten [64,64], w_att_conv [64,64]
// out = grid_sample(y, vgrid) -> [2,128,16,64,64] fp32

// ---------------- kernel A: per-channel mean of x ----------------
__global__ void kmean(const float* __restrict__ x, float* __restrict__ meanx) {
    int ch = blockIdx.x;  // 0..127  (n*64+c)
    const float4* base = (const float4*)(x + (size_t)ch * 65536);
    float s = 0.f;
    for (int j = threadIdx.x; j < 16384; j += 256) {
        float4 v = base[j];
        s += v.x + v.y + v.z + v.w;
    }
    __shared__ float red[256];
    red[threadIdx.x] = s;
    __syncthreads();
    for (int off = 128; off > 0; off >>= 1) {
        if (threadIdx.x < off) red[threadIdx.x] += red[threadIdx.x + off];
        __syncthreads();
    }
    if (threadIdx.x == 0) meanx[ch] = red[0] * (1.0f / 65536.0f);
}

// ---------------- kernel B: build W_comb^T per batch ----------------
// W_comb[n] = w_att_conv * diag(1+sigmoid(w_att_atten * (w_down_l * meanx))) * w_down_l
// stored transposed: wcombT[n][i][o]
__global__ void kprep(const float* __restrict__ wdl, const float* __restrict__ watt,
                      const float* __restrict__ wconv, const float* __restrict__ meanx,
                      float* __restrict__ wcombT) {
    int n = blockIdx.x;
    int c = threadIdx.x;  // 64 threads
    __shared__ float pooled[64], sc[64];
    float p = 0.f;
    for (int i = 0; i < 64; ++i) p += wdl[c * 64 + i] * meanx[n * 64 + i];
    pooled[c] = p;
    __syncthreads();
    float a = 0.f;
    for (int i = 0; i < 64; ++i) a += watt[c * 64 + i] * pooled[i];
    sc[c] = 1.f + 1.f / (1.f + expf(-a));
    __syncthreads();
    int o = c;
    for (int i = 0; i < 64; ++i) {
        float acc = 0.f;
        for (int j = 0; j < 64; ++j) acc += wconv[o * 64 + j] * sc[j] * wdl[j * 64 + i];
        wcombT[n * 4096 + i * 64 + o] = acc;
    }
}

// ---------------- kernel C: low2 = W_comb * x  (fused SE branch) ----------------
__global__ __launch_bounds__(256) void kconv1l(const float* __restrict__ x,
                                               const float* __restrict__ wcombT,
                                               float* __restrict__ low2) {
    int b = blockIdx.x;  // 512
    int n = b >> 8, tile = b & 255;
    __shared__ float4 Wl[1024];  // [i][o/4]
    const float4* src = (const float4*)(wcombT + n * 4096);
    for (int k = threadIdx.x; k < 1024; k += 256) Wl[k] = src[k];
    __syncthreads();
    int p = tile * 256 + threadIdx.x;
    float4 acc[16];
#pragma unroll
    for (int o = 0; o < 16; ++o) acc[o] = make_float4(0.f, 0.f, 0.f, 0.f);
    const float* xb = x + (size_t)n * 64 * 65536 + p;
    for (int i = 0; i < 64; ++i) {
        float xi = xb[(size_t)i * 65536];
#pragma unroll
        for (int o = 0; o < 16; ++o) {
            float4 w = Wl[i * 16 + o];
            acc[o].x = fmaf(w.x, xi, acc[o].x);
            acc[o].y = fmaf(w.y, xi, acc[o].y);
            acc[o].z = fmaf(w.z, xi, acc[o].z);
            acc[o].w = fmaf(w.w, xi, acc[o].w);
        }
    }
    float* ob = low2 + (size_t)n * 64 * 65536 + p;
#pragma unroll
    for (int o = 0; o < 16; ++o) {
        ob[(size_t)(4 * o + 0) * 65536] = acc[o].x;
        ob[(size_t)(4 * o + 1) * 65536] = acc[o].y;
        ob[(size_t)(4 * o + 2) * 65536] = acc[o].z;
        ob[(size_t)(4 * o + 3) * 65536] = acc[o].w;
    }
}

// ---------------- kernel D: hf = w_down_h * y ----------------
__global__ __launch_bounds__(256) void kconvh(const float* __restrict__ y,
                                              const float* __restrict__ wdh,
                                              float* __restrict__ hf) {
    int b = blockIdx.x;  // 64
    int n = b >> 5, tile = b & 31;
    __shared__ float Wh[8192];  // transposed [i][o]
    for (int k = threadIdx.x; k < 8192; k += 256) {
        int i = k >> 6, o = k & 63;
        Wh[k] = wdh[o * 128 + i];
    }
    __syncthreads();
    int p = tile * 256 + threadIdx.x;
    float4 acc[16];
#pragma unroll
    for (int o = 0; o < 16; ++o) acc[o] = make_float4(0.f, 0.f, 0.f, 0.f);
    const float* yb = y + (size_t)n * 128 * 8192 + p;
    const float4* Wh4 = (const float4*)Wh;
    for (int i = 0; i < 128; ++i) {
        float yi = yb[(size_t)i * 8192];
#pragma unroll
        for (int o = 0; o < 16; ++o) {
            float4 w = Wh4[i * 16 + o];
            acc[o].x = fmaf(w.x, yi, acc[o].x);
            acc[o].y = fmaf(w.y, yi, acc[o].y);
            acc[o].z = fmaf(w.z, yi, acc[o].z);
            acc[o].w = fmaf(w.w, yi, acc[o].w);
        }
    }
    float* ob = hf + (size_t)n * 64 * 8192 + p;
#pragma unroll
    for (int o = 0; o < 16; ++o) {
        ob[(size_t)(4 * o + 0) * 8192] = acc[o].x;
        ob[(size_t)(4 * o + 1) * 8192] = acc[o].y;
        ob[(size_t)(4 * o + 2) * 8192] = acc[o].z;
        ob[(size_t)(4 * o + 3) * 8192] = acc[o].w;
    }
}

// ---------------- kernel E: trilinear upsample (align_corners=True) ----------------
__global__ void kups(const float* __restrict__ hf, float* __restrict__ hfup) {
    int idx = blockIdx.x * 256 + threadIdx.x;  // 8388608 total
    int w = idx & 63, h = (idx >> 6) & 63, d = (idx >> 12) & 15;
    int c = (idx >> 16) & 63, n = idx >> 22;
    const float SD = 7.0f / 15.0f, SH = 31.0f / 63.0f;
    float pd = (float)d * SD, ph = (float)h * SH, pw = (float)w * SH;
    int z0 = (int)pd; if (z0 > 7) z0 = 7;
    int z1 = min(z0 + 1, 7); float fz = pd - (float)z0;
    int y0 = (int)ph; if (y0 > 31) y0 = 31;
    int y1 = min(y0 + 1, 31); float fy = ph - (float)y0;
    int x0 = (int)pw; if (x0 > 31) x0 = 31;
    int x1 = min(x0 + 1, 31); float fx = pw - (float)x0;
    const float* b = hf + (size_t)(n * 64 + c) * 8192;
    float v000 = b[(z0 * 32 + y0) * 32 + x0], v001 = b[(z0 * 32 + y0) * 32 + x1];
    float v010 = b[(z0 * 32 + y1) * 32 + x0], v011 = b[(z0 * 32 + y1) * 32 + x1];
    float v100 = b[(z1 * 32 + y0) * 32 + x0], v101 = b[(z1 * 32 + y0) * 32 + x1];
    float v110 = b[(z1 * 32 + y1) * 32 + x0], v111 = b[(z1 * 32 + y1) * 32 + x1];
    float c00 = v000 + (v001 - v000) * fx;
    float c01 = v010 + (v011 - v010) * fx;
    float c10 = v100 + (v101 - v100) * fx;
    float c11 = v110 + (v111 - v110) * fx;
    float c0 = c00 + (c01 - c00) * fy;
    float c1 = c10 + (c11 - c10) * fy;
    hfup[idx] = c0 + (c1 - c0) * fz;
}

// ---------------- kernel F: 3x3x3 conv (128->3) + grid add + normalize -> vgrid ----------------
__global__ __launch_bounds__(512) void kflow(const float* __restrict__ hfup,
                                             const float* __restrict__ low2,
                                             const float* __restrict__ wflow,
                                             float* __restrict__ vg) {
    int b = blockIdx.x;  // 256
    int n = b >> 7, t = b & 127;
    int td = t >> 5, th = (t >> 2) & 7, tw = t & 3;
    int d0 = td * 4, h0 = th * 8, w0 = tw * 16;
    __shared__ float in_t[4][6][10][18];  // 4320 floats
    __shared__ float wt[4][3][27];
    int tid = threadIdx.x;
    int zz = tid >> 7, yy = (tid >> 4) & 7, ww = tid & 15;
    float a0 = 0.f, a1 = 0.f, a2 = 0.f;
    for (int cc = 0; cc < 128; cc += 4) {
        const float* src = (cc < 64) ? (hfup + (size_t)(n * 64 + cc) * 65536)
                                     : (low2 + (size_t)(n * 64 + cc - 64) * 65536);
        __syncthreads();  // protect previous iteration reads
        for (int k = tid; k < 324; k += 512) {
            int c = k / 81, r = k % 81, o = r / 27, tap = r % 27;
            wt[c][o][tap] = wflow[(size_t)o * 128 * 27 + (size_t)(cc + c) * 27 + tap];
        }
        for (int e = tid; e < 4320; e += 512) {
            int c = e / 1080, r = e % 1080;
            int z = r / 180, r2 = r % 180, y = r2 / 18, xx = r2 % 18;
            int gz = d0 - 1 + z, gy = h0 - 1 + y, gx = w0 - 1 + xx;
            float v = 0.f;
            if ((unsigned)gz < 16u && (unsigned)gy < 64u && (unsigned)gx < 64u)
                v = src[(size_t)c * 65536 + gz * 4096 + gy * 64 + gx];
            in_t[c][z][y][xx] = v;
        }
        __syncthreads();
#pragma unroll
        for (int c = 0; c < 4; ++c) {
#pragma unroll
            for (int dz = 0; dz < 3; ++dz) {
#pragma unroll
                for (int dy = 0; dy < 3; ++dy) {
#pragma unroll
                    for (int dx = 0; dx < 3; ++dx) {
                        float v = in_t[c][zz + dz][yy + dy][ww + dx];
                        int tap = (dz * 3 + dy) * 3 + dx;
                        a0 = fmaf(wt[c][0][tap], v, a0);
                        a1 = fmaf(wt[c][1][tap], v, a1);
                        a2 = fmaf(wt[c][2][tap], v, a2);
                    }
                }
            }
        }
    }
    int d = d0 + zz, h = h0 + yy, w = w0 + ww;
    int p = d * 4096 + h * 64 + w;
    size_t base = (size_t)n * 3 * 65536;
    vg[base + p]             = ((float)w + a0) * (1.0f / 64.0f);
    vg[base + 65536 + p]     = ((float)h + a1) * (1.0f / 64.0f);
    vg[base + 2 * 65536 + p] = ((float)d + a2) * (1.0f / 16.0f);
}

// ---------------- kernel G: grid_sample (trilinear, zeros pad, align_corners=False) ----------------
__global__ __launch_bounds__(256) void ksample(const float* __restrict__ y,
                                               const float* __restrict__ vg,
                                               float* __restrict__ out) {
    int gid = blockIdx.x * 256 + threadIdx.x;  // 131072
    int n = gid >> 16, p = gid & 65535;
    size_t vb = (size_t)n * 3 * 65536;
    float gx = vg[vb + p], gy = vg[vb + 65536 + p], gz = vg[vb + 2 * 65536 + p];
    float ix = ((gx + 1.f) * 32.f - 1.f) * 0.5f;
    float iy = ((gy + 1.f) * 32.f - 1.f) * 0.5f;
    float iz = ((gz + 1.f) * 8.f - 1.f) * 0.5f;
    int x0 = (int)floorf(ix), y0 = (int)floorf(iy), z0 = (int)floorf(iz);
    float fx = ix - (float)x0, fy = iy - (float)y0, fz = iz - (float)z0;
    float wx[2] = {1.f - fx, fx}, wy[2] = {1.f - fy, fy}, wz[2] = {1.f - fz, fz};
    int idx8[8];
    float w8[8];
    float wsum = 0.f;
#pragma unroll
    for (int k = 0; k < 8; ++k) {
        int dz = k >> 2, dy = (k >> 1) & 1, dx = k & 1;
        int zc = z0 + dz, yc = y0 + dy, xc = x0 + dx;
        bool valid = ((unsigned)zc < 8u) && ((unsigned)yc < 32u) && ((unsigned)xc < 32u);
        int zcl = min(max(zc, 0), 7), ycl = min(max(yc, 0), 31), xcl = min(max(xc, 0), 31);
        idx8[k] = (zcl * 32 + ycl) * 32 + xcl;
        float wgt = wz[dz] * wy[dy] * wx[dx];
        w8[k] = valid ? wgt : 0.f;
        wsum += w8[k];
    }
    float* ob = out + (size_t)n * 128 * 65536 + p;
    const float* yb = y + (size_t)n * 128 * 8192;
    if (wsum == 0.f) {
        for (int c = 0; c < 128; ++c) ob[(size_t)c * 65536] = 0.f;
    } else {
        for (int c = 0; c < 128; ++c) {
            const float* bp = yb + (size_t)c * 8192;
            float acc = 0.f;
#pragma unroll
            for (int k = 0; k < 8; ++k) acc = fmaf(w8[k], bp[idx8[k]], acc);
            ob[(size_t)c * 65536] = acc;
        }
    }
}

extern "C" void kernel_launch(void* const* d_in, const int* in_sizes, int n_in,
                              void* d_out, int out_size, void* d_ws, size_t ws_size,
                              hipStream_t stream) {
    const float* x     = (const float*)d_in[0];
    const float* y     = (const float*)d_in[1];
    const float* wdh   = (const float*)d_in[2];
    const float* wdl   = (const float*)d_in[3];
    const float* wflow = (const float*)d_in[4];
    const float* watt  = (const float*)d_in[5];
    const float* wconv = (const float*)d_in[6];
    float* out = (float*)d_out;

    float* ws     = (float*)d_ws;
    float* meanx  = ws;                   // 128
    float* wcombT = meanx + 128;          // 8192
    float* hf     = wcombT + 8192;        // 1048576
    float* low2   = hf + 1048576;         // 8388608
    float* hfup   = low2 + 8388608;       // 8388608
    float* vg     = hfup + 8388608;       // 393216
    // total ~72.9 MB of workspace

    kmean<<<128, 256, 0, stream>>>(x, meanx);
    kprep<<<2, 64, 0, stream>>>(wdl, watt, wconv, meanx, wcombT);
    kconv1l<<<512, 256, 0, stream>>>(x, wcombT, low2);
    kconvh<<<64, 256, 0, stream>>>(y, wdh, hf);
    kups<<<32768, 256, 0, stream>>>(hf, hfup);
    kflow<<<256, 512, 0, stream>>>(hfup, low2, wflow, vg);
    ksample<<<512, 256, 0, stream>>>(y, vg, out);
}

// Round 3
// 331.870 us; speedup vs baseline: 1.4573x; 1.4573x over previous
//
#include <hip/hip_runtime.h>
#include <math.h>

// x [2,64,16,64,64], y [2,128,8,32,32]
// w_down_h [64,128], w_down_l [64,64], w_flow [3,128,3,3,3],
// w_att_atten [64,64], w_att_conv [64,64]
// out = grid_sample(y, vgrid) -> [2,128,16,64,64] fp32

// ---------------- kernel A: per-channel mean of x ----------------
__global__ void kmean(const float* __restrict__ x, float* __restrict__ meanx) {
    int ch = blockIdx.x;  // 0..127  (n*64+c)
    const float4* base = (const float4*)(x + (size_t)ch * 65536);
    float s = 0.f;
    for (int j = threadIdx.x; j < 16384; j += 256) {
        float4 v = base[j];
        s += v.x + v.y + v.z + v.w;
    }
    __shared__ float red[256];
    red[threadIdx.x] = s;
    __syncthreads();
    for (int off = 128; off > 0; off >>= 1) {
        if (threadIdx.x < off) red[threadIdx.x] += red[threadIdx.x + off];
        __syncthreads();
    }
    if (threadIdx.x == 0) meanx[ch] = red[0] * (1.0f / 65536.0f);
}

// ---------------- kernel B: build W_comb^T per batch ----------------
__global__ void kprep(const float* __restrict__ wdl, const float* __restrict__ watt,
                      const float* __restrict__ wconv, const float* __restrict__ meanx,
                      float* __restrict__ wcombT) {
    int n = blockIdx.x;
    int c = threadIdx.x;  // 64 threads
    __shared__ float pooled[64], sc[64];
    float p = 0.f;
    for (int i = 0; i < 64; ++i) p += wdl[c * 64 + i] * meanx[n * 64 + i];
    pooled[c] = p;
    __syncthreads();
    float a = 0.f;
    for (int i = 0; i < 64; ++i) a += watt[c * 64 + i] * pooled[i];
    sc[c] = 1.f + 1.f / (1.f + expf(-a));
    __syncthreads();
    int o = c;
    for (int i = 0; i < 64; ++i) {
        float acc = 0.f;
        for (int j = 0; j < 64; ++j) acc += wconv[o * 64 + j] * sc[j] * wdl[j * 64 + i];
        wcombT[n * 4096 + i * 64 + o] = acc;
    }
}

// ---------------- kernel C: low2 = W_comb * x ----------------
__global__ __launch_bounds__(256) void kconv1l(const float* __restrict__ x,
                                               const float* __restrict__ wcombT,
                                               float* __restrict__ low2) {
    int b = blockIdx.x;  // 512
    int n = b >> 8, tile = b & 255;
    __shared__ float4 Wl[1024];
    const float4* src = (const float4*)(wcombT + n * 4096);
    for (int k = threadIdx.x; k < 1024; k += 256) Wl[k] = src[k];
    __syncthreads();
    int p = tile * 256 + threadIdx.x;
    float4 acc[16];
#pragma unroll
    for (int o = 0; o < 16; ++o) acc[o] = make_float4(0.f, 0.f, 0.f, 0.f);
    const float* xb = x + (size_t)n * 64 * 65536 + p;
    for (int i = 0; i < 64; ++i) {
        float xi = xb[(size_t)i * 65536];
#pragma unroll
        for (int o = 0; o < 16; ++o) {
            float4 w = Wl[i * 16 + o];
            acc[o].x = fmaf(w.x, xi, acc[o].x);
            acc[o].y = fmaf(w.y, xi, acc[o].y);
            acc[o].z = fmaf(w.z, xi, acc[o].z);
            acc[o].w = fmaf(w.w, xi, acc[o].w);
        }
    }
    float* ob = low2 + (size_t)n * 64 * 65536 + p;
#pragma unroll
    for (int o = 0; o < 16; ++o) {
        ob[(size_t)(4 * o + 0) * 65536] = acc[o].x;
        ob[(size_t)(4 * o + 1) * 65536] = acc[o].y;
        ob[(size_t)(4 * o + 2) * 65536] = acc[o].z;
        ob[(size_t)(4 * o + 3) * 65536] = acc[o].w;
    }
}

// ---------------- kernel D: hf = w_down_h * y ----------------
__global__ __launch_bounds__(256) void kconvh(const float* __restrict__ y,
                                              const float* __restrict__ wdh,
                                              float* __restrict__ hf) {
    int b = blockIdx.x;  // 64
    int n = b >> 5, tile = b & 31;
    __shared__ float Wh[8192];
    for (int k = threadIdx.x; k < 8192; k += 256) {
        int i = k >> 6, o = k & 63;
        Wh[k] = wdh[o * 128 + i];
    }
    __syncthreads();
    int p = tile * 256 + threadIdx.x;
    float4 acc[16];
#pragma unroll
    for (int o = 0; o < 16; ++o) acc[o] = make_float4(0.f, 0.f, 0.f, 0.f);
    const float* yb = y + (size_t)n * 128 * 8192 + p;
    const float4* Wh4 = (const float4*)Wh;
    for (int i = 0; i < 128; ++i) {
        float yi = yb[(size_t)i * 8192];
#pragma unroll
        for (int o = 0; o < 16; ++o) {
            float4 w = Wh4[i * 16 + o];
            acc[o].x = fmaf(w.x, yi, acc[o].x);
            acc[o].y = fmaf(w.y, yi, acc[o].y);
            acc[o].z = fmaf(w.z, yi, acc[o].z);
            acc[o].w = fmaf(w.w, yi, acc[o].w);
        }
    }
    float* ob = hf + (size_t)n * 64 * 8192 + p;
#pragma unroll
    for (int o = 0; o < 16; ++o) {
        ob[(size_t)(4 * o + 0) * 8192] = acc[o].x;
        ob[(size_t)(4 * o + 1) * 8192] = acc[o].y;
        ob[(size_t)(4 * o + 2) * 8192] = acc[o].z;
        ob[(size_t)(4 * o + 3) * 8192] = acc[o].w;
    }
}

// ---------------- kernel E: trilinear upsample (align_corners=True) ----------------
__global__ void kups(const float* __restrict__ hf, float* __restrict__ hfup) {
    int idx = blockIdx.x * 256 + threadIdx.x;  // 8388608 total
    int w = idx & 63, h = (idx >> 6) & 63, d = (idx >> 12) & 15;
    int c = (idx >> 16) & 63, n = idx >> 22;
    const float SD = 7.0f / 15.0f, SH = 31.0f / 63.0f;
    float pd = (float)d * SD, ph = (float)h * SH, pw = (float)w * SH;
    int z0 = (int)pd; if (z0 > 7) z0 = 7;
    int z1 = min(z0 + 1, 7); float fz = pd - (float)z0;
    int y0 = (int)ph; if (y0 > 31) y0 = 31;
    int y1 = min(y0 + 1, 31); float fy = ph - (float)y0;
    int x0 = (int)pw; if (x0 > 31) x0 = 31;
    int x1 = min(x0 + 1, 31); float fx = pw - (float)x0;
    const float* b = hf + (size_t)(n * 64 + c) * 8192;
    float v000 = b[(z0 * 32 + y0) * 32 + x0], v001 = b[(z0 * 32 + y0) * 32 + x1];
    float v010 = b[(z0 * 32 + y1) * 32 + x0], v011 = b[(z0 * 32 + y1) * 32 + x1];
    float v100 = b[(z1 * 32 + y0) * 32 + x0], v101 = b[(z1 * 32 + y0) * 32 + x1];
    float v110 = b[(z1 * 32 + y1) * 32 + x0], v111 = b[(z1 * 32 + y1) * 32 + x1];
    float c00 = v000 + (v001 - v000) * fx;
    float c01 = v010 + (v011 - v010) * fx;
    float c10 = v100 + (v101 - v100) * fx;
    float c11 = v110 + (v111 - v110) * fx;
    float c0 = c00 + (c01 - c00) * fy;
    float c1 = c10 + (c11 - c10) * fy;
    hfup[idx] = c0 + (c1 - c0) * fz;
}

// ---------------- kernel F: 3x3x3 conv partials (channel-split x16) ----------------
// Each block: one 4x16x16 output tile, 8 input channels. Writes partial sums.
// part layout: part[((split*2 + n)*3 + o)*65536 + p]
__global__ __launch_bounds__(256) void kflowp(const float* __restrict__ hfup,
                                              const float* __restrict__ low2,
                                              const float* __restrict__ wflow,
                                              float* __restrict__ part) {
    const int b = blockIdx.x;              // 2048
    const int split = b & 15;
    const int tileid = b >> 4;             // 0..127
    const int n = tileid >> 6;
    const int t = tileid & 63;
    const int td = t >> 4, th = (t >> 2) & 3, tw = t & 3;
    const int d0 = td * 4, h0 = th * 16, w0 = tw * 16;

    const int tid = threadIdx.x;
    const int tx = tid & 15;        // output x
    const int ty = (tid >> 4) & 7;  // output y pair
    const int tz = tid >> 7;        // output z pair

    __shared__ float in_t[2][6][18][19];  // padded x-stride 19, 16416 B

    float acc[3][2][2];
#pragma unroll
    for (int o = 0; o < 3; ++o)
#pragma unroll
        for (int q = 0; q < 2; ++q)
#pragma unroll
            for (int r = 0; r < 2; ++r) acc[o][q][r] = 0.f;

    for (int ci = 0; ci < 8; ci += 2) {
        __syncthreads();  // protect prior-iteration reads
        for (int ch = 0; ch < 2; ++ch) {
            int cg = split * 8 + ci + ch;
            const float* src = (cg < 64)
                ? hfup + (size_t)(n * 64 + cg) * 65536
                : low2 + (size_t)(n * 64 + cg - 64) * 65536;
            for (int e = tid; e < 1944; e += 256) {
                int z = e / 324;
                int rr = e - z * 324;
                int yy = rr / 18;
                int xx = rr - yy * 18;
                int gz = d0 - 1 + z, gy = h0 - 1 + yy, gx = w0 - 1 + xx;
                float v = 0.f;
                if ((unsigned)gz < 16u && (unsigned)gy < 64u && (unsigned)gx < 64u)
                    v = src[gz * 4096 + gy * 64 + gx];
                in_t[ch][z][yy][xx] = v;
            }
        }
        __syncthreads();
#pragma unroll
        for (int ch = 0; ch < 2; ++ch) {
            int cg = split * 8 + ci + ch;
            const float* wb = wflow + cg * 27;  // + o*3456 + tap
#pragma unroll
            for (int zi = 0; zi < 4; ++zi) {
#pragma unroll
                for (int yi = 0; yi < 4; ++yi) {
                    float v0 = in_t[ch][tz * 2 + zi][ty * 2 + yi][tx + 0];
                    float v1 = in_t[ch][tz * 2 + zi][ty * 2 + yi][tx + 1];
                    float v2 = in_t[ch][tz * 2 + zi][ty * 2 + yi][tx + 2];
#pragma unroll
                    for (int q = 0; q < 2; ++q) {
                        const int dz = zi - q;
                        if (dz < 0 || dz > 2) continue;
#pragma unroll
                        for (int r = 0; r < 2; ++r) {
                            const int dy = yi - r;
                            if (dy < 0 || dy > 2) continue;
#pragma unroll
                            for (int o = 0; o < 3; ++o) {
                                const float* wp = wb + o * 3456 + (dz * 3 + dy) * 3;
                                float a = acc[o][q][r];
                                a = fmaf(wp[0], v0, a);
                                a = fmaf(wp[1], v1, a);
                                a = fmaf(wp[2], v2, a);
                                acc[o][q][r] = a;
                            }
                        }
                    }
                }
            }
        }
    }

    const int od = d0 + tz * 2, oh = h0 + ty * 2, ow = w0 + tx;
    size_t base = ((size_t)(split * 2 + n)) * 3 * 65536;
#pragma unroll
    for (int o = 0; o < 3; ++o)
#pragma unroll
        for (int q = 0; q < 2; ++q)
#pragma unroll
            for (int r = 0; r < 2; ++r) {
                int p = (od + q) * 4096 + (oh + r) * 64 + ow;
                part[base + (size_t)o * 65536 + p] = acc[o][q][r];
            }
}

// ---------------- kernel F2: combine partials + grid + normalize -> vgrid ----------------
__global__ void kcomb(const float* __restrict__ part, float* __restrict__ vg) {
    int gid = blockIdx.x * 256 + threadIdx.x;  // 131072
    int n = gid >> 16, p = gid & 65535;
    float s0 = 0.f, s1 = 0.f, s2 = 0.f;
    for (int s = 0; s < 16; ++s) {
        const float* bp = part + ((size_t)(s * 2 + n)) * 3 * 65536 + p;
        s0 += bp[0];
        s1 += bp[65536];
        s2 += bp[131072];
    }
    int w = p & 63, h = (p >> 6) & 63, d = p >> 12;
    size_t vb = (size_t)n * 3 * 65536;
    vg[vb + p]          = ((float)w + s0) * (1.0f / 64.0f);
    vg[vb + 65536 + p]  = ((float)h + s1) * (1.0f / 64.0f);
    vg[vb + 131072 + p] = ((float)d + s2) * (1.0f / 16.0f);
}

// ---------------- kernel G: grid_sample ----------------
__global__ __launch_bounds__(256) void ksample(const float* __restrict__ y,
                                               const float* __restrict__ vg,
                                               float* __restrict__ out) {
    int gid = blockIdx.x * 256 + threadIdx.x;  // 131072
    int n = gid >> 16, p = gid & 65535;
    size_t vb = (size_t)n * 3 * 65536;
    float gx = vg[vb + p], gy = vg[vb + 65536 + p], gz = vg[vb + 2 * 65536 + p];
    float ix = ((gx + 1.f) * 32.f - 1.f) * 0.5f;
    float iy = ((gy + 1.f) * 32.f - 1.f) * 0.5f;
    float iz = ((gz + 1.f) * 8.f - 1.f) * 0.5f;
    int x0 = (int)floorf(ix), y0 = (int)floorf(iy), z0 = (int)floorf(iz);
    float fx = ix - (float)x0, fy = iy - (float)y0, fz = iz - (float)z0;
    float wx[2] = {1.f - fx, fx}, wy[2] = {1.f - fy, fy}, wz[2] = {1.f - fz, fz};
    int idx8[8];
    float w8[8];
    float wsum = 0.f;
#pragma unroll
    for (int k = 0; k < 8; ++k) {
        int dz = k >> 2, dy = (k >> 1) & 1, dx = k & 1;
        int zc = z0 + dz, yc = y0 + dy, xc = x0 + dx;
        bool valid = ((unsigned)zc < 8u) && ((unsigned)yc < 32u) && ((unsigned)xc < 32u);
        int zcl = min(max(zc, 0), 7), ycl = min(max(yc, 0), 31), xcl = min(max(xc, 0), 31);
        idx8[k] = (zcl * 32 + ycl) * 32 + xcl;
        float wgt = wz[dz] * wy[dy] * wx[dx];
        w8[k] = valid ? wgt : 0.f;
        wsum += w8[k];
    }
    float* ob = out + (size_t)n * 128 * 65536 + p;
    const float* yb = y + (size_t)n * 128 * 8192;
    if (wsum == 0.f) {
        for (int c = 0; c < 128; ++c) ob[(size_t)c * 65536] = 0.f;
    } else {
        for (int c = 0; c < 128; ++c) {
            const float* bp = yb + (size_t)c * 8192;
            float acc = 0.f;
#pragma unroll
            for (int k = 0; k < 8; ++k) acc = fmaf(w8[k], bp[idx8[k]], acc);
            ob[(size_t)c * 65536] = acc;
        }
    }
}

extern "C" void kernel_launch(void* const* d_in, const int* in_sizes, int n_in,
                              void* d_out, int out_size, void* d_ws, size_t ws_size,
                              hipStream_t stream) {
    const float* x     = (const float*)d_in[0];
    const float* y     = (const float*)d_in[1];
    const float* wdh   = (const float*)d_in[2];
    const float* wdl   = (const float*)d_in[3];
    const float* wflow = (const float*)d_in[4];
    const float* watt  = (const float*)d_in[5];
    const float* wconv = (const float*)d_in[6];
    float* out = (float*)d_out;

    float* ws     = (float*)d_ws;
    float* meanx  = ws;                   // 128
    float* wcombT = meanx + 128;          // 8192
    float* hf     = wcombT + 8192;        // 1048576
    float* low2   = hf + 1048576;         // 8388608
    float* hfup   = low2 + 8388608;       // 8388608
    float* vg     = hfup + 8388608;       // 393216

    // partials live in d_out (16*2*3*65536 = 6.29M floats <= 16.7M):
    // fully written by kflowp before kcomb reads; ksample overwrites all of d_out.
    float* part = out;

    kmean<<<128, 256, 0, stream>>>(x, meanx);
    kprep<<<2, 64, 0, stream>>>(wdl, watt, wconv, meanx, wcombT);
    kconv1l<<<512, 256, 0, stream>>>(x, wcombT, low2);
    kconvh<<<64, 256, 0, stream>>>(y, wdh, hf);
    kups<<<32768, 256, 0, stream>>>(hf, hfup);
    kflowp<<<2048, 256, 0, stream>>>(hfup, low2, wflow, part);
    kcomb<<<512, 256, 0, stream>>>(part, vg);
    ksample<<<512, 256, 0, stream>>>(y, vg, out);
}

// Round 4
// 308.161 us; speedup vs baseline: 1.5694x; 1.0769x over previous
//
#include <hip/hip_runtime.h>
#include <math.h>

// x [2,64,16,64,64], y [2,128,8,32,32]
// w_down_h [64,128], w_down_l [64,64], w_flow [3,128,3,3,3],
// w_att_atten [64,64], w_att_conv [64,64]
// out = grid_sample(y, vgrid) -> [2,128,16,64,64] fp32

// ---------------- kernel A: per-channel mean of x ----------------
__global__ void kmean(const float* __restrict__ x, float* __restrict__ meanx) {
    int ch = blockIdx.x;  // 0..127  (n*64+c)
    const float4* base = (const float4*)(x + (size_t)ch * 65536);
    float s = 0.f;
    for (int j = threadIdx.x; j < 16384; j += 256) {
        float4 v = base[j];
        s += v.x + v.y + v.z + v.w;
    }
    __shared__ float red[256];
    red[threadIdx.x] = s;
    __syncthreads();
    for (int off = 128; off > 0; off >>= 1) {
        if (threadIdx.x < off) red[threadIdx.x] += red[threadIdx.x + off];
        __syncthreads();
    }
    if (threadIdx.x == 0) meanx[ch] = red[0] * (1.0f / 65536.0f);
}

// ---------------- kernel B: build W_comb^T per batch ----------------
__global__ void kprep(const float* __restrict__ wdl, const float* __restrict__ watt,
                      const float* __restrict__ wconv, const float* __restrict__ meanx,
                      float* __restrict__ wcombT) {
    int n = blockIdx.x;
    int c = threadIdx.x;  // 64 threads
    __shared__ float pooled[64], sc[64];
    float p = 0.f;
    for (int i = 0; i < 64; ++i) p += wdl[c * 64 + i] * meanx[n * 64 + i];
    pooled[c] = p;
    __syncthreads();
    float a = 0.f;
    for (int i = 0; i < 64; ++i) a += watt[c * 64 + i] * pooled[i];
    sc[c] = 1.f + 1.f / (1.f + expf(-a));
    __syncthreads();
    int o = c;
    for (int i = 0; i < 64; ++i) {
        float acc = 0.f;
        for (int j = 0; j < 64; ++j) acc += wconv[o * 64 + j] * sc[j] * wdl[j * 64 + i];
        wcombT[n * 4096 + i * 64 + o] = acc;
    }
}

// ---------------- kernel C: low2 = W_comb * x ----------------
__global__ __launch_bounds__(256) void kconv1l(const float* __restrict__ x,
                                               const float* __restrict__ wcombT,
                                               float* __restrict__ low2) {
    int b = blockIdx.x;  // 512
    int n = b >> 8, tile = b & 255;
    __shared__ float4 Wl[1024];
    const float4* src = (const float4*)(wcombT + n * 4096);
    for (int k = threadIdx.x; k < 1024; k += 256) Wl[k] = src[k];
    __syncthreads();
    int p = tile * 256 + threadIdx.x;
    float4 acc[16];
#pragma unroll
    for (int o = 0; o < 16; ++o) acc[o] = make_float4(0.f, 0.f, 0.f, 0.f);
    const float* xb = x + (size_t)n * 64 * 65536 + p;
    for (int i = 0; i < 64; ++i) {
        float xi = xb[(size_t)i * 65536];
#pragma unroll
        for (int o = 0; o < 16; ++o) {
            float4 w = Wl[i * 16 + o];
            acc[o].x = fmaf(w.x, xi, acc[o].x);
            acc[o].y = fmaf(w.y, xi, acc[o].y);
            acc[o].z = fmaf(w.z, xi, acc[o].z);
            acc[o].w = fmaf(w.w, xi, acc[o].w);
        }
    }
    float* ob = low2 + (size_t)n * 64 * 65536 + p;
#pragma unroll
    for (int o = 0; o < 16; ++o) {
        ob[(size_t)(4 * o + 0) * 65536] = acc[o].x;
        ob[(size_t)(4 * o + 1) * 65536] = acc[o].y;
        ob[(size_t)(4 * o + 2) * 65536] = acc[o].z;
        ob[(size_t)(4 * o + 3) * 65536] = acc[o].w;
    }
}

// ---------------- kernel D: hf = w_down_h * y ----------------
__global__ __launch_bounds__(256) void kconvh(const float* __restrict__ y,
                                              const float* __restrict__ wdh,
                                              float* __restrict__ hf) {
    int b = blockIdx.x;  // 64
    int n = b >> 5, tile = b & 31;
    __shared__ float Wh[8192];
    for (int k = threadIdx.x; k < 8192; k += 256) {
        int i = k >> 6, o = k & 63;
        Wh[k] = wdh[o * 128 + i];
    }
    __syncthreads();
    int p = tile * 256 + threadIdx.x;
    float4 acc[16];
#pragma unroll
    for (int o = 0; o < 16; ++o) acc[o] = make_float4(0.f, 0.f, 0.f, 0.f);
    const float* yb = y + (size_t)n * 128 * 8192 + p;
    const float4* Wh4 = (const float4*)Wh;
    for (int i = 0; i < 128; ++i) {
        float yi = yb[(size_t)i * 8192];
#pragma unroll
        for (int o = 0; o < 16; ++o) {
            float4 w = Wh4[i * 16 + o];
            acc[o].x = fmaf(w.x, yi, acc[o].x);
            acc[o].y = fmaf(w.y, yi, acc[o].y);
            acc[o].z = fmaf(w.z, yi, acc[o].z);
            acc[o].w = fmaf(w.w, yi, acc[o].w);
        }
    }
    float* ob = hf + (size_t)n * 64 * 8192 + p;
#pragma unroll
    for (int o = 0; o < 16; ++o) {
        ob[(size_t)(4 * o + 0) * 8192] = acc[o].x;
        ob[(size_t)(4 * o + 1) * 8192] = acc[o].y;
        ob[(size_t)(4 * o + 2) * 8192] = acc[o].z;
        ob[(size_t)(4 * o + 3) * 8192] = acc[o].w;
    }
}

// ---------------- kernel E: trilinear upsample (align_corners=True) ----------------
__global__ void kups(const float* __restrict__ hf, float* __restrict__ hfup) {
    int idx = blockIdx.x * 256 + threadIdx.x;  // 8388608 total
    int w = idx & 63, h = (idx >> 6) & 63, d = (idx >> 12) & 15;
    int c = (idx >> 16) & 63, n = idx >> 22;
    const float SD = 7.0f / 15.0f, SH = 31.0f / 63.0f;
    float pd = (float)d * SD, ph = (float)h * SH, pw = (float)w * SH;
    int z0 = (int)pd; if (z0 > 7) z0 = 7;
    int z1 = min(z0 + 1, 7); float fz = pd - (float)z0;
    int y0 = (int)ph; if (y0 > 31) y0 = 31;
    int y1 = min(y0 + 1, 31); float fy = ph - (float)y0;
    int x0 = (int)pw; if (x0 > 31) x0 = 31;
    int x1 = min(x0 + 1, 31); float fx = pw - (float)x0;
    const float* b = hf + (size_t)(n * 64 + c) * 8192;
    float v000 = b[(z0 * 32 + y0) * 32 + x0], v001 = b[(z0 * 32 + y0) * 32 + x1];
    float v010 = b[(z0 * 32 + y1) * 32 + x0], v011 = b[(z0 * 32 + y1) * 32 + x1];
    float v100 = b[(z1 * 32 + y0) * 32 + x0], v101 = b[(z1 * 32 + y0) * 32 + x1];
    float v110 = b[(z1 * 32 + y1) * 32 + x0], v111 = b[(z1 * 32 + y1) * 32 + x1];
    float c00 = v000 + (v001 - v000) * fx;
    float c01 = v010 + (v011 - v010) * fx;
    float c10 = v100 + (v101 - v100) * fx;
    float c11 = v110 + (v111 - v110) * fx;
    float c0 = c00 + (c01 - c00) * fy;
    float c1 = c10 + (c11 - c10) * fy;
    hfup[idx] = c0 + (c1 - c0) * fz;
}

// ---------------- kernel F: 3x3x3 conv partials (channel-split x16) ----------------
__global__ __launch_bounds__(256) void kflowp(const float* __restrict__ hfup,
                                              const float* __restrict__ low2,
                                              const float* __restrict__ wflow,
                                              float* __restrict__ part) {
    const int b = blockIdx.x;              // 2048
    const int split = b & 15;
    const int tileid = b >> 4;             // 0..127
    const int n = tileid >> 6;
    const int t = tileid & 63;
    const int td = t >> 4, th = (t >> 2) & 3, tw = t & 3;
    const int d0 = td * 4, h0 = th * 16, w0 = tw * 16;

    const int tid = threadIdx.x;
    const int tx = tid & 15;        // output x
    const int ty = (tid >> 4) & 7;  // output y pair
    const int tz = tid >> 7;        // output z pair

    __shared__ float in_t[2][6][18][19];  // padded x-stride 19, 16416 B

    float acc[3][2][2];
#pragma unroll
    for (int o = 0; o < 3; ++o)
#pragma unroll
        for (int q = 0; q < 2; ++q)
#pragma unroll
            for (int r = 0; r < 2; ++r) acc[o][q][r] = 0.f;

    for (int ci = 0; ci < 8; ci += 2) {
        __syncthreads();  // protect prior-iteration reads
        for (int ch = 0; ch < 2; ++ch) {
            int cg = split * 8 + ci + ch;
            const float* src = (cg < 64)
                ? hfup + (size_t)(n * 64 + cg) * 65536
                : low2 + (size_t)(n * 64 + cg - 64) * 65536;
            for (int e = tid; e < 1944; e += 256) {
                int z = e / 324;
                int rr = e - z * 324;
                int yy = rr / 18;
                int xx = rr - yy * 18;
                int gz = d0 - 1 + z, gy = h0 - 1 + yy, gx = w0 - 1 + xx;
                float v = 0.f;
                if ((unsigned)gz < 16u && (unsigned)gy < 64u && (unsigned)gx < 64u)
                    v = src[gz * 4096 + gy * 64 + gx];
                in_t[ch][z][yy][xx] = v;
            }
        }
        __syncthreads();
#pragma unroll
        for (int ch = 0; ch < 2; ++ch) {
            int cg = split * 8 + ci + ch;
            const float* wb = wflow + cg * 27;  // + o*3456 + tap
#pragma unroll
            for (int zi = 0; zi < 4; ++zi) {
#pragma unroll
                for (int yi = 0; yi < 4; ++yi) {
                    float v0 = in_t[ch][tz * 2 + zi][ty * 2 + yi][tx + 0];
                    float v1 = in_t[ch][tz * 2 + zi][ty * 2 + yi][tx + 1];
                    float v2 = in_t[ch][tz * 2 + zi][ty * 2 + yi][tx + 2];
#pragma unroll
                    for (int q = 0; q < 2; ++q) {
                        const int dz = zi - q;
                        if (dz < 0 || dz > 2) continue;
#pragma unroll
                        for (int r = 0; r < 2; ++r) {
                            const int dy = yi - r;
                            if (dy < 0 || dy > 2) continue;
#pragma unroll
                            for (int o = 0; o < 3; ++o) {
                                const float* wp = wb + o * 3456 + (dz * 3 + dy) * 3;
                                float a = acc[o][q][r];
                                a = fmaf(wp[0], v0, a);
                                a = fmaf(wp[1], v1, a);
                                a = fmaf(wp[2], v2, a);
                                acc[o][q][r] = a;
                            }
                        }
                    }
                }
            }
        }
    }

    const int od = d0 + tz * 2, oh = h0 + ty * 2, ow = w0 + tx;
    size_t base = ((size_t)(split * 2 + n)) * 3 * 65536;
#pragma unroll
    for (int o = 0; o < 3; ++o)
#pragma unroll
        for (int q = 0; q < 2; ++q)
#pragma unroll
            for (int r = 0; r < 2; ++r) {
                int p = (od + q) * 4096 + (oh + r) * 64 + ow;
                part[base + (size_t)o * 65536 + p] = acc[o][q][r];
            }
}

// ---------------- kernel F2: combine partials + grid + normalize -> vgrid ----------------
__global__ void kcomb(const float* __restrict__ part, float* __restrict__ vg) {
    int gid = blockIdx.x * 256 + threadIdx.x;  // 131072
    int n = gid >> 16, p = gid & 65535;
    float s0 = 0.f, s1 = 0.f, s2 = 0.f;
    for (int s = 0; s < 16; ++s) {
        const float* bp = part + ((size_t)(s * 2 + n)) * 3 * 65536 + p;
        s0 += bp[0];
        s1 += bp[65536];
        s2 += bp[131072];
    }
    int w = p & 63, h = (p >> 6) & 63, d = p >> 12;
    size_t vb = (size_t)n * 3 * 65536;
    vg[vb + p]          = ((float)w + s0) * (1.0f / 64.0f);
    vg[vb + 65536 + p]  = ((float)h + s1) * (1.0f / 64.0f);
    vg[vb + 131072 + p] = ((float)d + s2) * (1.0f / 16.0f);
}

// ---------------- kernel G: grid_sample (channel-split x16, 8 ch/thread) ----------------
__global__ __launch_bounds__(256) void ksample(const float* __restrict__ y,
                                               const float* __restrict__ vg,
                                               float* __restrict__ out) {
    const int bx = blockIdx.x;          // 8192
    const int cchunk = bx & 15;         // 8-channel chunk
    const int tile = bx >> 4;           // 0..511
    const int n = tile >> 8;
    const int p = ((tile & 255) << 8) | threadIdx.x;

    size_t vb = (size_t)n * 3 * 65536;
    float gx = vg[vb + p], gy = vg[vb + 65536 + p], gz = vg[vb + 2 * 65536 + p];
    float ix = ((gx + 1.f) * 32.f - 1.f) * 0.5f;
    float iy = ((gy + 1.f) * 32.f - 1.f) * 0.5f;
    float iz = ((gz + 1.f) * 8.f - 1.f) * 0.5f;
    int x0 = (int)floorf(ix), y0 = (int)floorf(iy), z0 = (int)floorf(iz);
    float fx = ix - (float)x0, fy = iy - (float)y0, fz = iz - (float)z0;
    float wx[2] = {1.f - fx, fx}, wy[2] = {1.f - fy, fy}, wz[2] = {1.f - fz, fz};
    int idx8[8];
    float w8[8];
    float wsum = 0.f;
#pragma unroll
    for (int k = 0; k < 8; ++k) {
        int dz = k >> 2, dy = (k >> 1) & 1, dx = k & 1;
        int zc = z0 + dz, yc = y0 + dy, xc = x0 + dx;
        bool valid = ((unsigned)zc < 8u) && ((unsigned)yc < 32u) && ((unsigned)xc < 32u);
        int zcl = min(max(zc, 0), 7), ycl = min(max(yc, 0), 31), xcl = min(max(xc, 0), 31);
        idx8[k] = (zcl * 32 + ycl) * 32 + xcl;
        float wgt = wz[dz] * wy[dy] * wx[dx];
        w8[k] = valid ? wgt : 0.f;
        wsum += w8[k];
    }
    float* ob = out + ((size_t)(n * 128 + cchunk * 8)) * 65536 + p;
    const float* yb = y + ((size_t)(n * 128 + cchunk * 8)) * 8192;
    if (wsum == 0.f) {
#pragma unroll
        for (int c = 0; c < 8; ++c) ob[(size_t)c * 65536] = 0.f;
    } else {
#pragma unroll
        for (int c = 0; c < 8; ++c) {
            const float* bp = yb + (size_t)c * 8192;
            float acc = 0.f;
#pragma unroll
            for (int k = 0; k < 8; ++k) acc = fmaf(w8[k], bp[idx8[k]], acc);
            ob[(size_t)c * 65536] = acc;
        }
    }
}

extern "C" void kernel_launch(void* const* d_in, const int* in_sizes, int n_in,
                              void* d_out, int out_size, void* d_ws, size_t ws_size,
                              hipStream_t stream) {
    const float* x     = (const float*)d_in[0];
    const float* y     = (const float*)d_in[1];
    const float* wdh   = (const float*)d_in[2];
    const float* wdl   = (const float*)d_in[3];
    const float* wflow = (const float*)d_in[4];
    const float* watt  = (const float*)d_in[5];
    const float* wconv = (const float*)d_in[6];
    float* out = (float*)d_out;

    float* ws     = (float*)d_ws;
    float* meanx  = ws;                   // 128
    float* wcombT = meanx + 128;          // 8192
    float* hf     = wcombT + 8192;        // 1048576
    float* low2   = hf + 1048576;         // 8388608
    float* hfup   = low2 + 8388608;       // 8388608
    float* vg     = hfup + 8388608;       // 393216

    // partials live in d_out (16*2*3*65536 = 6.29M floats <= 16.7M):
    // fully written by kflowp before kcomb reads; ksample overwrites all of d_out.
    float* part = out;

    kmean<<<128, 256, 0, stream>>>(x, meanx);
    kprep<<<2, 64, 0, stream>>>(wdl, watt, wconv, meanx, wcombT);
    kconv1l<<<512, 256, 0, stream>>>(x, wcombT, low2);
    kconvh<<<64, 256, 0, stream>>>(y, wdh, hf);
    kups<<<32768, 256, 0, stream>>>(hf, hfup);
    kflowp<<<2048, 256, 0, stream>>>(hfup, low2, wflow, part);
    kcomb<<<512, 256, 0, stream>>>(part, vg);
    ksample<<<8192, 256, 0, stream>>>(y, vg, out);
}

// Round 5
// 271.443 us; speedup vs baseline: 1.7817x; 1.1353x over previous
//
#include <hip/hip_runtime.h>
#include <math.h>

// x [2,64,16,64,64], y [2,128,8,32,32]
// w_down_h [64,128], w_down_l [64,64], w_flow [3,128,3,3,3],
// w_att_atten [64,64], w_att_conv [64,64]
// out = grid_sample(y, vgrid) -> [2,128,16,64,64] fp32

// ---------------- kernel A: per-channel mean of x ----------------
__global__ void kmean(const float* __restrict__ x, float* __restrict__ meanx) {
    int ch = blockIdx.x;  // 0..127  (n*64+c)
    const float4* base = (const float4*)(x + (size_t)ch * 65536);
    float s = 0.f;
    for (int j = threadIdx.x; j < 16384; j += 256) {
        float4 v = base[j];
        s += v.x + v.y + v.z + v.w;
    }
    __shared__ float red[256];
    red[threadIdx.x] = s;
    __syncthreads();
    for (int off = 128; off > 0; off >>= 1) {
        if (threadIdx.x < off) red[threadIdx.x] += red[threadIdx.x + off];
        __syncthreads();
    }
    if (threadIdx.x == 0) meanx[ch] = red[0] * (1.0f / 65536.0f);
}

// ---------------- kernel B: build W_comb^T per batch ----------------
__global__ void kprep(const float* __restrict__ wdl, const float* __restrict__ watt,
                      const float* __restrict__ wconv, const float* __restrict__ meanx,
                      float* __restrict__ wcombT) {
    int n = blockIdx.x;
    int c = threadIdx.x;  // 64 threads
    __shared__ float pooled[64], sc[64];
    float p = 0.f;
    for (int i = 0; i < 64; ++i) p += wdl[c * 64 + i] * meanx[n * 64 + i];
    pooled[c] = p;
    __syncthreads();
    float a = 0.f;
    for (int i = 0; i < 64; ++i) a += watt[c * 64 + i] * pooled[i];
    sc[c] = 1.f + 1.f / (1.f + expf(-a));
    __syncthreads();
    int o = c;
    for (int i = 0; i < 64; ++i) {
        float acc = 0.f;
        for (int j = 0; j < 64; ++j) acc += wconv[o * 64 + j] * sc[j] * wdl[j * 64 + i];
        wcombT[n * 4096 + i * 64 + o] = acc;
    }
}

// ---------------- kernel C: low2 = W_comb * x ----------------
__global__ __launch_bounds__(256) void kconv1l(const float* __restrict__ x,
                                               const float* __restrict__ wcombT,
                                               float* __restrict__ low2) {
    int b = blockIdx.x;  // 512
    int n = b >> 8, tile = b & 255;
    __shared__ float4 Wl[1024];
    const float4* src = (const float4*)(wcombT + n * 4096);
    for (int k = threadIdx.x; k < 1024; k += 256) Wl[k] = src[k];
    __syncthreads();
    int p = tile * 256 + threadIdx.x;
    float4 acc[16];
#pragma unroll
    for (int o = 0; o < 16; ++o) acc[o] = make_float4(0.f, 0.f, 0.f, 0.f);
    const float* xb = x + (size_t)n * 64 * 65536 + p;
    for (int i = 0; i < 64; ++i) {
        float xi = xb[(size_t)i * 65536];
#pragma unroll
        for (int o = 0; o < 16; ++o) {
            float4 w = Wl[i * 16 + o];
            acc[o].x = fmaf(w.x, xi, acc[o].x);
            acc[o].y = fmaf(w.y, xi, acc[o].y);
            acc[o].z = fmaf(w.z, xi, acc[o].z);
            acc[o].w = fmaf(w.w, xi, acc[o].w);
        }
    }
    float* ob = low2 + (size_t)n * 64 * 65536 + p;
#pragma unroll
    for (int o = 0; o < 16; ++o) {
        ob[(size_t)(4 * o + 0) * 65536] = acc[o].x;
        ob[(size_t)(4 * o + 1) * 65536] = acc[o].y;
        ob[(size_t)(4 * o + 2) * 65536] = acc[o].z;
        ob[(size_t)(4 * o + 3) * 65536] = acc[o].w;
    }
}

// ---------------- kernel D: hf = w_down_h * y ----------------
__global__ __launch_bounds__(256) void kconvh(const float* __restrict__ y,
                                              const float* __restrict__ wdh,
                                              float* __restrict__ hf) {
    int b = blockIdx.x;  // 64
    int n = b >> 5, tile = b & 31;
    __shared__ float Wh[8192];
    for (int k = threadIdx.x; k < 8192; k += 256) {
        int i = k >> 6, o = k & 63;
        Wh[k] = wdh[o * 128 + i];
    }
    __syncthreads();
    int p = tile * 256 + threadIdx.x;
    float4 acc[16];
#pragma unroll
    for (int o = 0; o < 16; ++o) acc[o] = make_float4(0.f, 0.f, 0.f, 0.f);
    const float* yb = y + (size_t)n * 128 * 8192 + p;
    const float4* Wh4 = (const float4*)Wh;
    for (int i = 0; i < 128; ++i) {
        float yi = yb[(size_t)i * 8192];
#pragma unroll
        for (int o = 0; o < 16; ++o) {
            float4 w = Wh4[i * 16 + o];
            acc[o].x = fmaf(w.x, yi, acc[o].x);
            acc[o].y = fmaf(w.y, yi, acc[o].y);
            acc[o].z = fmaf(w.z, yi, acc[o].z);
            acc[o].w = fmaf(w.w, yi, acc[o].w);
        }
    }
    float* ob = hf + (size_t)n * 64 * 8192 + p;
#pragma unroll
    for (int o = 0; o < 16; ++o) {
        ob[(size_t)(4 * o + 0) * 8192] = acc[o].x;
        ob[(size_t)(4 * o + 1) * 8192] = acc[o].y;
        ob[(size_t)(4 * o + 2) * 8192] = acc[o].z;
        ob[(size_t)(4 * o + 3) * 8192] = acc[o].w;
    }
}

// ---------------- kernel E: trilinear upsample (align_corners=True) ----------------
__global__ void kups(const float* __restrict__ hf, float* __restrict__ hfup) {
    int idx = blockIdx.x * 256 + threadIdx.x;  // 8388608 total
    int w = idx & 63, h = (idx >> 6) & 63, d = (idx >> 12) & 15;
    int c = (idx >> 16) & 63, n = idx >> 22;
    const float SD = 7.0f / 15.0f, SH = 31.0f / 63.0f;
    float pd = (float)d * SD, ph = (float)h * SH, pw = (float)w * SH;
    int z0 = (int)pd; if (z0 > 7) z0 = 7;
    int z1 = min(z0 + 1, 7); float fz = pd - (float)z0;
    int y0 = (int)ph; if (y0 > 31) y0 = 31;
    int y1 = min(y0 + 1, 31); float fy = ph - (float)y0;
    int x0 = (int)pw; if (x0 > 31) x0 = 31;
    int x1 = min(x0 + 1, 31); float fx = pw - (float)x0;
    const float* b = hf + (size_t)(n * 64 + c) * 8192;
    float v000 = b[(z0 * 32 + y0) * 32 + x0], v001 = b[(z0 * 32 + y0) * 32 + x1];
    float v010 = b[(z0 * 32 + y1) * 32 + x0], v011 = b[(z0 * 32 + y1) * 32 + x1];
    float v100 = b[(z1 * 32 + y0) * 32 + x0], v101 = b[(z1 * 32 + y0) * 32 + x1];
    float v110 = b[(z1 * 32 + y1) * 32 + x0], v111 = b[(z1 * 32 + y1) * 32 + x1];
    float c00 = v000 + (v001 - v000) * fx;
    float c01 = v010 + (v011 - v010) * fx;
    float c10 = v100 + (v101 - v100) * fx;
    float c11 = v110 + (v111 - v110) * fx;
    float c0 = c00 + (c01 - c00) * fy;
    float c1 = c10 + (c11 - c10) * fy;
    hfup[idx] = c0 + (c1 - c0) * fz;
}

// ---------------- kernel F: 3x3x3 conv partials (channel-split x16) ----------------
__global__ __launch_bounds__(256) void kflowp(const float* __restrict__ hfup,
                                              const float* __restrict__ low2,
                                              const float* __restrict__ wflow,
                                              float* __restrict__ part) {
    const int b = blockIdx.x;              // 2048
    const int split = b & 15;
    const int tileid = b >> 4;             // 0..127
    const int n = tileid >> 6;
    const int t = tileid & 63;
    const int td = t >> 4, th = (t >> 2) & 3, tw = t & 3;
    const int d0 = td * 4, h0 = th * 16, w0 = tw * 16;

    const int tid = threadIdx.x;
    const int tx = tid & 15;        // output x
    const int ty = (tid >> 4) & 7;  // output y pair
    const int tz = tid >> 7;        // output z pair

    __shared__ float in_t[2][6][18][19];  // padded x-stride 19, 16416 B

    float acc[3][2][2];
#pragma unroll
    for (int o = 0; o < 3; ++o)
#pragma unroll
        for (int q = 0; q < 2; ++q)
#pragma unroll
            for (int r = 0; r < 2; ++r) acc[o][q][r] = 0.f;

    for (int ci = 0; ci < 8; ci += 2) {
        __syncthreads();  // protect prior-iteration reads
        for (int ch = 0; ch < 2; ++ch) {
            int cg = split * 8 + ci + ch;
            const float* src = (cg < 64)
                ? hfup + (size_t)(n * 64 + cg) * 65536
                : low2 + (size_t)(n * 64 + cg - 64) * 65536;
            for (int e = tid; e < 1944; e += 256) {
                int z = e / 324;
                int rr = e - z * 324;
                int yy = rr / 18;
                int xx = rr - yy * 18;
                int gz = d0 - 1 + z, gy = h0 - 1 + yy, gx = w0 - 1 + xx;
                float v = 0.f;
                if ((unsigned)gz < 16u && (unsigned)gy < 64u && (unsigned)gx < 64u)
                    v = src[gz * 4096 + gy * 64 + gx];
                in_t[ch][z][yy][xx] = v;
            }
        }
        __syncthreads();
#pragma unroll
        for (int ch = 0; ch < 2; ++ch) {
            int cg = split * 8 + ci + ch;
            const float* wb = wflow + cg * 27;  // + o*3456 + tap
#pragma unroll
            for (int zi = 0; zi < 4; ++zi) {
#pragma unroll
                for (int yi = 0; yi < 4; ++yi) {
                    float v0 = in_t[ch][tz * 2 + zi][ty * 2 + yi][tx + 0];
                    float v1 = in_t[ch][tz * 2 + zi][ty * 2 + yi][tx + 1];
                    float v2 = in_t[ch][tz * 2 + zi][ty * 2 + yi][tx + 2];
#pragma unroll
                    for (int q = 0; q < 2; ++q) {
                        const int dz = zi - q;
                        if (dz < 0 || dz > 2) continue;
#pragma unroll
                        for (int r = 0; r < 2; ++r) {
                            const int dy = yi - r;
                            if (dy < 0 || dy > 2) continue;
#pragma unroll
                            for (int o = 0; o < 3; ++o) {
                                const float* wp = wb + o * 3456 + (dz * 3 + dy) * 3;
                                float a = acc[o][q][r];
                                a = fmaf(wp[0], v0, a);
                                a = fmaf(wp[1], v1, a);
                                a = fmaf(wp[2], v2, a);
                                acc[o][q][r] = a;
                            }
                        }
                    }
                }
            }
        }
    }

    const int od = d0 + tz * 2, oh = h0 + ty * 2, ow = w0 + tx;
    size_t base = ((size_t)(split * 2 + n)) * 3 * 65536;
#pragma unroll
    for (int o = 0; o < 3; ++o)
#pragma unroll
        for (int q = 0; q < 2; ++q)
#pragma unroll
            for (int r = 0; r < 2; ++r) {
                int p = (od + q) * 4096 + (oh + r) * 64 + ow;
                part[base + (size_t)o * 65536 + p] = acc[o][q][r];
            }
}

// ---------------- kernel F2: combine partials + grid + normalize -> vgrid ----------------
__global__ void kcomb(const float* __restrict__ part, float* __restrict__ vg) {
    int gid = blockIdx.x * 256 + threadIdx.x;  // 131072
    int n = gid >> 16, p = gid & 65535;
    float s0 = 0.f, s1 = 0.f, s2 = 0.f;
    for (int s = 0; s < 16; ++s) {
        const float* bp = part + ((size_t)(s * 2 + n)) * 3 * 65536 + p;
        s0 += bp[0];
        s1 += bp[65536];
        s2 += bp[131072];
    }
    int w = p & 63, h = (p >> 6) & 63, d = p >> 12;
    size_t vb = (size_t)n * 3 * 65536;
    vg[vb + p]          = ((float)w + s0) * (1.0f / 64.0f);
    vg[vb + 65536 + p]  = ((float)h + s1) * (1.0f / 64.0f);
    vg[vb + 131072 + p] = ((float)d + s2) * (1.0f / 16.0f);
}

// ---------------- kernel T: transpose y -> channel-last yt [n][8192][128] ----------------
__global__ __launch_bounds__(256) void ktrans(const float* __restrict__ y,
                                              float* __restrict__ yt) {
    int b = blockIdx.x;       // 512
    int n = b >> 8;
    int rem = b & 255;        // 2 c-tiles * 128 s-tiles
    int ct = rem >> 7, st = rem & 127;
    int c0 = ct * 64, s0 = st * 64;
    __shared__ float t[64][65];
    int tx = threadIdx.x & 63, ty = threadIdx.x >> 6;  // 4 rows/pass
#pragma unroll
    for (int k = 0; k < 16; ++k)
        t[ty + 4 * k][tx] = y[((size_t)(n * 128 + c0 + ty + 4 * k)) * 8192 + s0 + tx];
    __syncthreads();
#pragma unroll
    for (int k = 0; k < 16; ++k)
        yt[((size_t)(n * 8192 + s0 + ty + 4 * k)) * 128 + c0 + tx] = t[tx][ty + 4 * k];
}

// ---------------- kernel G: grid_sample, channel-last gathers ----------------
// One wave = one output point; lane covers channels {2*lane, 2*lane+1} via float2.
// Output transposed back through padded LDS for coalesced stores.
__global__ __launch_bounds__(256) void ksample(const float* __restrict__ yt,
                                               const float* __restrict__ vg,
                                               float* __restrict__ out) {
    const int b = blockIdx.x;        // 2048
    const int n = b >> 10;
    const int p0 = (b & 1023) << 6;  // 64 points per block
    const int tid = threadIdx.x;
    const int lane = tid & 63;
    const int wv = tid >> 6;         // 0..3

    __shared__ float lds[128 * 65];  // [c][pt], pad 65

    const float* ytn = yt + (size_t)n * 8192 * 128;
    const size_t vb = (size_t)n * 3 * 65536;

    for (int q = 0; q < 16; ++q) {
        const int pt = wv * 16 + q;  // 0..63, wave-uniform
        const int p = p0 + pt;
        float gx = vg[vb + p], gy = vg[vb + 65536 + p], gz = vg[vb + 131072 + p];
        float ix = ((gx + 1.f) * 32.f - 1.f) * 0.5f;
        float iy = ((gy + 1.f) * 32.f - 1.f) * 0.5f;
        float iz = ((gz + 1.f) * 8.f - 1.f) * 0.5f;
        int x0 = (int)floorf(ix), y0 = (int)floorf(iy), z0 = (int)floorf(iz);
        float fx = ix - (float)x0, fy = iy - (float)y0, fz = iz - (float)z0;
        float wx[2] = {1.f - fx, fx}, wy[2] = {1.f - fy, fy}, wz[2] = {1.f - fz, fz};
        int idx8[8];
        float w8[8];
        float wsum = 0.f;
#pragma unroll
        for (int k = 0; k < 8; ++k) {
            int dz = k >> 2, dy = (k >> 1) & 1, dx = k & 1;
            int zc = z0 + dz, yc = y0 + dy, xc = x0 + dx;
            bool valid = ((unsigned)zc < 8u) && ((unsigned)yc < 32u) && ((unsigned)xc < 32u);
            int zcl = min(max(zc, 0), 7), ycl = min(max(yc, 0), 31), xcl = min(max(xc, 0), 31);
            idx8[k] = (zcl * 32 + ycl) * 32 + xcl;
            float wgt = wz[dz] * wy[dy] * wx[dx];
            w8[k] = valid ? wgt : 0.f;
            wsum += w8[k];
        }
        float ax = 0.f, ay = 0.f;
        if (wsum != 0.f) {
#pragma unroll
            for (int k = 0; k < 8; ++k) {
                const float2 v = *(const float2*)(ytn + (size_t)idx8[k] * 128 + 2 * lane);
                ax = fmaf(w8[k], v.x, ax);
                ay = fmaf(w8[k], v.y, ay);
            }
        }
        lds[(2 * lane) * 65 + pt] = ax;
        lds[(2 * lane + 1) * 65 + pt] = ay;
    }
    __syncthreads();
    // coalesced store: 128 channel-rows of 64 points
    const int pw = tid & 63, cw = tid >> 6;
    float* ob = out + (size_t)n * 128 * 65536 + p0 + pw;
#pragma unroll
    for (int k = 0; k < 32; ++k) {
        int c = k * 4 + cw;
        ob[(size_t)c * 65536] = lds[c * 65 + pw];
    }
}

extern "C" void kernel_launch(void* const* d_in, const int* in_sizes, int n_in,
                              void* d_out, int out_size, void* d_ws, size_t ws_size,
                              hipStream_t stream) {
    const float* x     = (const float*)d_in[0];
    const float* y     = (const float*)d_in[1];
    const float* wdh   = (const float*)d_in[2];
    const float* wdl   = (const float*)d_in[3];
    const float* wflow = (const float*)d_in[4];
    const float* watt  = (const float*)d_in[5];
    const float* wconv = (const float*)d_in[6];
    float* out = (float*)d_out;

    float* ws     = (float*)d_ws;
    float* meanx  = ws;                   // 128
    float* wcombT = meanx + 128;          // 8192
    float* hf     = wcombT + 8192;        // 1048576
    float* low2   = hf + 1048576;         // 8388608
    float* hfup   = low2 + 8388608;       // 8388608
    float* vg     = hfup + 8388608;       // 393216

    // partials live in d_out (6.29M floats <= 16.7M); ksample later overwrites all of d_out.
    float* part = out;
    // yt (2.1M floats) reuses the hfup region — hfup is dead after kflowp.
    float* yt = hfup;

    kmean<<<128, 256, 0, stream>>>(x, meanx);
    kprep<<<2, 64, 0, stream>>>(wdl, watt, wconv, meanx, wcombT);
    kconv1l<<<512, 256, 0, stream>>>(x, wcombT, low2);
    kconvh<<<64, 256, 0, stream>>>(y, wdh, hf);
    kups<<<32768, 256, 0, stream>>>(hf, hfup);
    kflowp<<<2048, 256, 0, stream>>>(hfup, low2, wflow, part);
    kcomb<<<512, 256, 0, stream>>>(part, vg);
    ktrans<<<512, 256, 0, stream>>>(y, yt);      // after kflowp: hfup region now free
    ksample<<<2048, 256, 0, stream>>>(yt, vg, out);
}